// Round 18
// baseline (105.396 us; speedup 1.0000x reference)
//
#include <hip/hip_runtime.h>
#include <hip/hip_bf16.h>

// ---------------- problem constants ----------------
#define T_STEPS 16
#define BATCH   64
#define M_ROWS  1024          // T*B
#define K_DIM   60000
#define N1      200
#define N2      50
#define N3      2
#define HN      (M_ROWS * N1) // 204800 elems per [m][n] slab
#define BK      32            // k per step

typedef __attribute__((ext_vector_type(8)))  short bf16x8;
typedef __attribute__((ext_vector_type(16))) float f32x16;

// pack 8 f32 -> 8 bf16 (compiler emits v_cvt_pk_bf16_f32)
static __device__ __forceinline__ bf16x8 cvt8(float4 lo, float4 hi) {
    union { bf16x8 v; __hip_bfloat162 h[4]; } u;
    u.h[0] = __float22bfloat162_rn(make_float2(lo.x, lo.y));
    u.h[1] = __float22bfloat162_rn(make_float2(lo.z, lo.w));
    u.h[2] = __float22bfloat162_rn(make_float2(hi.x, hi.y));
    u.h[3] = __float22bfloat162_rn(make_float2(hi.z, hi.w));
    return u.v;
}

static __device__ __forceinline__ float bf2f(unsigned short u) {
    unsigned int x = (unsigned int)u << 16;
    return __uint_as_float(x);
}

// LGKM-only barrier: LDS writes visible; in-flight global->register loads
// are NOT drained (no global_load_lds in this kernel, so vmcnt never
// guards LDS state). __syncthreads() would drain vmcnt(0) too.
static __device__ __forceinline__ void lgkm_barrier() {
    __builtin_amdgcn_sched_barrier(0);
    asm volatile("s_waitcnt lgkmcnt(0)\n\ts_barrier" ::: "memory");
    __builtin_amdgcn_sched_barrier(0);
}

// Kernel 1: part[s] = X[:, seg_s] @ W1[:, seg_s].T   (bf16 partials out)
// THIS ROUND: 3 blocks/CU via halved accumulator.
//   Wave-tile 64m x 32n (acc = 2 x f32x16 = 32 VGPR, was 64). Block tile
//   128m x 128n, 8 waves (2m x 4n), 2 n-tiles cover the padded 256 cols.
//   launch_bounds(512,6): 85-VGPR cap -> 6 waves/SIMD -> 3 blocks/CU
//   (LDS 2x16KB = 32KB/block -> 96KB/CU). 3 independent HBM streams per CU
//   (was 2) -- the r8-r16 probes showed schedule is not the binder; stream
//   count is.
// Same as r17 otherwise: granule-XOR swizzle, reg-staged f32 operands,
// 2-slot pA / 1-slot pB, lgkm-only barriers, junk trim (B rows >= 200 never
// loaded; nt=1/wn=3 waves skip the MFMA cluster -- cols 224-255 are junk).
// nt is the fastest grid dim so the 2 blocks sharing an X slice are
// co-XCD and temporally adjacent (X read once, L2 serves the twin).
template <int KSEG, int KSTEPS, int NWG>
__global__ __launch_bounds__(512, 6)
void gemm_lds(const float* __restrict__ x,
              const float* __restrict__ w1,
              unsigned short* __restrict__ part) {
    __shared__ __align__(16) char smem[2][16384];   // [A 8KB][B 8KB] per buf

    const int tid = threadIdx.x;
    const int l   = tid & 63;
    const int wv  = tid >> 6;          // 0..7
    const int wm  = wv & 1;            // wave m index (2)
    const int wn  = wv >> 1;           // wave n index (4)

    // bijective XCD-chunked swizzle (NWG % 8 == 0): the 16 blocks sharing a
    // k-segment are logically consecutive -> (mostly) one XCD's L2.
    const int hw      = blockIdx.y * 16 + blockIdx.x;
    const int logical = (hw & 7) * (NWG / 8) + (hw >> 3);
    const int s    = logical >> 4;
    const int mtnt = logical & 15;
    const int mt   = mtnt >> 1;
    const int nt   = mtnt & 1;         // fastest: X-sharing twins adjacent

    const int m0 = mt * 128;
    const int n0 = nt * 128;
    const int k0 = s * KSEG;

    // A staging: thread -> (row ar = tid>>2, 8-f32 granule ag = tid&3)
    const int ar = tid >> 2;            // 0..127
    const int ag = tid & 3;
    const float* asrc = x + (size_t)(m0 + ar) * K_DIM + k0 + ag * 8;
    const int aw_off = ar * 64 + ((ag ^ ((ar >> 1) & 3)) << 4);   // swizzled

    // B staging: same decomposition; global row = n0 + br
    const int br = tid >> 2;            // 0..127
    const int bg = tid & 3;
    const int grow = n0 + br;
    const bool bvalid = grow < N1;      // junk rows: no load, no write
    const float* bsrc = w1 + (size_t)grow * K_DIM + k0 + bg * 8;
    const int bw_off = 8192 + br * 64 + ((bg ^ ((br >> 1) & 3)) << 4);

    // wave activity: nt=1, wn=3 covers cols 224-255 -> all junk
    const bool wactive = (n0 + wn * 32) < N1;

    f32x16 acc[2];                      // fm = 0,1 (rows +0 / +32)
    #pragma unroll
    for (int i = 0; i < 2; ++i)
        #pragma unroll
        for (int q = 0; q < 16; ++q) acc[i][q] = 0.f;

    float4 pA[2][2];                    // A reg slots, [step parity][2]
    float4 pB[2];                       // B 1-slot (8 f32)

    // ---- prologue: stage step 0 directly; preload A(1), B(1) regs ----
    {
        float4 a0 = *(const float4*)asrc;
        float4 a1 = *(const float4*)(asrc + 4);
        float4 b0, b1;
        if (bvalid) {
            b0 = *(const float4*)bsrc;
            b1 = *(const float4*)(bsrc + 4);
        }
        pA[1][0] = *(const float4*)(asrc + BK);
        pA[1][1] = *(const float4*)(asrc + BK + 4);
        if (bvalid) {
            pB[0] = *(const float4*)(bsrc + BK);
            pB[1] = *(const float4*)(bsrc + BK + 4);
        }
        *(bf16x8*)(smem[0] + aw_off) = cvt8(a0, a1);
        if (bvalid)
            *(bf16x8*)(smem[0] + bw_off) = cvt8(b0, b1);
    }
    lgkm_barrier();

    const int fr = l & 31;              // fragment row/col
    const int fh = (l >> 5) * 16;       // 16B half within 32B k-chunk

    #pragma unroll
    for (int it = 0; it < KSTEPS; ++it) {
        const int cur = it & 1;
        const bool more = (it + 1) < KSTEPS;

        // phase 1: issue A(it+2) register loads (consumed at step it+1 ph3)
        if (more) {
            const int jn = (it + 2 < KSTEPS) ? (it + 2) : (KSTEPS - 1);
            pA[cur][0] = *(const float4*)(asrc + jn * BK);   // slot (it+2)&1 == cur
            pA[cur][1] = *(const float4*)(asrc + jn * BK + 4);
        }
        __builtin_amdgcn_sched_barrier(0);

        // phase 2: swizzled ds_read + MFMA (32x32x16) on buf[cur]
        if (wactive) {
            const char* ab = smem[cur];
            const char* bb = smem[cur] + 8192;
            #pragma unroll
            for (int kk = 0; kk < 2; ++kk) {
                const int r0 = wm * 64 + fr;
                const int r1 = wm * 64 + 32 + fr;
                const int n  = wn * 32 + fr;
                bf16x8 a0 = *(const bf16x8*)(ab + r0 * 64 + ((kk * 32 + fh) ^ (((r0 >> 1) & 3) << 4)));
                bf16x8 a1 = *(const bf16x8*)(ab + r1 * 64 + ((kk * 32 + fh) ^ (((r1 >> 1) & 3) << 4)));
                bf16x8 bv = *(const bf16x8*)(bb + n * 64 + ((kk * 32 + fh) ^ (((n >> 1) & 3) << 4)));
                acc[0] = __builtin_amdgcn_mfma_f32_32x32x16_bf16(a0, bv, acc[0], 0, 0, 0);
                acc[1] = __builtin_amdgcn_mfma_f32_32x32x16_bf16(a1, bv, acc[1], 0, 0, 0);
            }
        }
        __builtin_amdgcn_sched_barrier(0);

        // phase 3: cvt + swizzled ds_write of A(it+1), B(it+1) into buf^1;
        // then refill pB with B(it+2) (full-step latency cover).
        if (more) {
            char* nb = smem[cur ^ 1];
            *(bf16x8*)(nb + aw_off) = cvt8(pA[cur ^ 1][0], pA[cur ^ 1][1]);
            if (bvalid) {
                *(bf16x8*)(nb + bw_off) = cvt8(pB[0], pB[1]);
                if ((it + 2) < KSTEPS) {
                    const float* bp = bsrc + (size_t)(it + 2) * BK;
                    pB[0] = *(const float4*)bp;
                    pB[1] = *(const float4*)(bp + 4);
                }
            }
            lgkm_barrier();   // LDS visible; global prefetch stays in flight
        }
    }

    // epilogue: store cols < 200 as bf16, part layout [s][m][n], ld = 200
    // C/D layout (m74/m101): col = l&31, row = (reg&3) + 8*(reg>>2) + 4*(l>>5)
    const int col = l & 31;
    const int rhi = (l >> 5) * 4;
    const int gn  = n0 + wn * 32 + col;
    if (gn < N1) {
        #pragma unroll
        for (int fm = 0; fm < 2; ++fm) {
            const int gmb = m0 + wm * 64 + fm * 32 + rhi;
            #pragma unroll
            for (int r = 0; r < 16; ++r) {
                const int gm = gmb + (r & 3) + 8 * (r >> 2);
                __hip_bfloat16 hv = __float2bfloat16(acc[fm][r]);
                part[(size_t)s * HN + (size_t)gm * N1 + gn] = *(unsigned short*)&hv;
            }
        }
    }
}

// Kernel 2: dense deterministic s-reduction of bf16 partials -> f32 h1.
template <int KSPLIT>
__global__ __launch_bounds__(256)
void reduce_kernel(const unsigned short* __restrict__ part, float* __restrict__ h1) {
    const size_t f = ((size_t)blockIdx.x * 256 + threadIdx.x) * 2;   // < 204800
    float a0 = 0.f, a1 = 0.f;
    #pragma unroll 25
    for (int s = 0; s < KSPLIT; ++s) {
        const unsigned int v = *(const unsigned int*)(part + (size_t)s * HN + f);
        a0 += bf2f((unsigned short)(v & 0xFFFFu));
        a1 += bf2f((unsigned short)(v >> 16));
    }
    h1[f]     = a0;
    h1[f + 1] = a1;
}

// Kernel 3: fused LIF tail, latency-tolerant. One block per batch b.
__global__ __launch_bounds__(256)
void tail_kernel(const float* __restrict__ h1,
                 const float* __restrict__ w2, const float* __restrict__ w3,
                 float* __restrict__ out) {
    __shared__ float w2s[N2 * N1];                  // 40 KB
    __shared__ float w3s[N3 * N2];
    __shared__ unsigned long long msk[T_STEPS][4];

    const int b    = blockIdx.x;
    const int i    = threadIdx.x;
    const int wv   = i >> 6;
    const int lane = i & 63;

    for (int o = i; o < (N2 * N1) / 4; o += 256)
        ((float4*)w2s)[o] = ((const float4*)w2)[o];
    if (i < N3 * N2) w3s[i] = w3[i];

    float h[T_STEPS];
    #pragma unroll
    for (int t = 0; t < T_STEPS; ++t)
        h[t] = (i < N1) ? h1[(size_t)(t * BATCH + b) * N1 + i] : 0.f;

    float v1 = 0.f;
    #pragma unroll
    for (int t = 0; t < T_STEPS; ++t) {
        v1 += (h[t] - v1) * 0.5f;
        bool sp = (v1 - 1.0f) >= 0.f;
        unsigned long long m = __ballot(sp);
        if (sp) v1 = 0.f;
        if (lane == 0) msk[t][wv] = m;
    }
    __syncthreads();

    if (wv == 0) {
        float v2 = 0.f, v3 = 0.f;
        for (int t = 0; t < T_STEPS; ++t) {
            float h2 = 0.f;
            if (lane < N2) {
                #pragma unroll
                for (int w = 0; w < 4; ++w) {
                    unsigned long long m = msk[t][w];
                    while (m) {
                        int lz = __builtin_ctzll(m);
                        m &= m - 1;
                        h2 += w2s[lane * N1 + (w * 64 + lz)];
                    }
                }
            }
            v2 += (h2 - v2) * 0.5f;
            bool sp2 = (v2 - 1.0f) >= 0.f;
            unsigned long long bal2 = __ballot(sp2);
            if (sp2) v2 = 0.f;

            float h3 = 0.f;
            if (lane < N3) {
                unsigned long long m = bal2;
                while (m) {
                    int j = __builtin_ctzll(m);
                    m &= m - 1;
                    h3 += w3s[lane * N2 + j];
                }
            }
            v3 += (h3 - v3) * 0.5f;
            bool sp3 = (v3 - 1.0f) >= 0.f;
            if (lane < N3)
                out[(size_t)(t * BATCH + b) * N3 + lane] = sp3 ? 1.f : 0.f;
            if (sp3) v3 = 0.f;
        }
    }
}

extern "C" void kernel_launch(void* const* d_in, const int* in_sizes, int n_in,
                              void* d_out, int out_size, void* d_ws, size_t ws_size,
                              hipStream_t stream) {
    const float* x  = (const float*)d_in[0];   // [16,64,150,400] -> [1024][60000]
    const float* w1 = (const float*)d_in[1];   // [200][60000]
    const float* w2 = (const float*)d_in[2];   // [50][200]
    const float* w3 = (const float*)d_in[3];   // [2][50]
    float* out = (float*)d_out;                // [16][64][2]

    // ws layout: part bf16 [KSPLIT][1024][200], h1 f32
    const size_t h1_bytes  = (size_t)HN * 4;                 // 0.82 MB
    const size_t need125 = (size_t)125 * HN * 2 + h1_bytes;  // ~52 MB
    const bool big = ws_size >= need125;

    const int ksplit = big ? 125 : 25;
    unsigned short* part = (unsigned short*)d_ws;
    float* h1 = (float*)((char*)d_ws + (size_t)ksplit * HN * 2);

    if (big) {
        dim3 g(16, 125);
        gemm_lds<480, 15, 2000><<<g, 512, 0, stream>>>(x, w1, part);
        reduce_kernel<125><<<HN / 512, 256, 0, stream>>>(part, h1);
    } else {
        dim3 g(16, 25);
        gemm_lds<2400, 75, 400><<<g, 512, 0, stream>>>(x, w1, part);
        reduce_kernel<25><<<HN / 512, 256, 0, stream>>>(part, h1);
    }
    tail_kernel<<<BATCH, 256, 0, stream>>>(h1, w2, w3, out);
}

// Round 19
// 98.928 us; speedup vs baseline: 1.0654x; 1.0654x over previous
//
#include <hip/hip_runtime.h>
#include <hip/hip_bf16.h>

// ---------------- problem constants ----------------
#define T_STEPS 16
#define BATCH   64
#define M_ROWS  1024          // T*B
#define K_DIM   60000
#define N1      200
#define N2      50
#define N3      2
#define HN      (M_ROWS * N1) // 204800 elems per [m][n] slab
#define BK      32            // k per step

typedef __attribute__((ext_vector_type(8)))  short bf16x8;
typedef __attribute__((ext_vector_type(16))) float f32x16;

// pack 8 f32 -> 8 bf16 (compiler emits v_cvt_pk_bf16_f32)
static __device__ __forceinline__ bf16x8 cvt8(float4 lo, float4 hi) {
    union { bf16x8 v; __hip_bfloat162 h[4]; } u;
    u.h[0] = __float22bfloat162_rn(make_float2(lo.x, lo.y));
    u.h[1] = __float22bfloat162_rn(make_float2(lo.z, lo.w));
    u.h[2] = __float22bfloat162_rn(make_float2(hi.x, hi.y));
    u.h[3] = __float22bfloat162_rn(make_float2(hi.z, hi.w));
    return u.v;
}

static __device__ __forceinline__ float bf2f(unsigned short u) {
    unsigned int x = (unsigned int)u << 16;
    return __uint_as_float(x);
}

// LGKM-only barrier: LDS writes visible; in-flight global->register loads
// are NOT drained (no global_load_lds in this kernel, so vmcnt never
// guards LDS state). __syncthreads() would drain vmcnt(0) too.
// sched_barrier fences kept here per rule #18 (pin nothing ACROSS the
// barrier), but the step body is otherwise unpinned this round.
static __device__ __forceinline__ void lgkm_barrier() {
    __builtin_amdgcn_sched_barrier(0);
    asm volatile("s_waitcnt lgkmcnt(0)\n\ts_barrier" ::: "memory");
    __builtin_amdgcn_sched_barrier(0);
}

// Kernel 1: part[s] = X[:, seg_s] @ W1[:, seg_s].T   (bf16 partials out)
// EXACT r17 structure (best: 99.9 us) with ONE change: the intra-step
// sched_barrier(0) phase pins are REMOVED. With the loop fully unrolled,
// smem[cur]/smem[cur^1] are compile-time-distinct, so the compiler can
// legally interleave ph3's cvt+ds_write into the MFMA shadow and sink/hoist
// load-issue into slack -- the pins were forbidding exactly that (m141
// lesson: order-pinning defeats the scheduler).
// Everything else unchanged: 128m x 256n, BK=32, 8 waves 2x4, 32x32x16
// MFMA, granule-XOR swizzle, reg-staged f32 operands, 2-slot pA / 1-slot
// pB, lgkm-only barriers, junk trim, 2 blocks/CU.
template <int KSEG, int KSTEPS, int NWG>
__global__ __launch_bounds__(512, 4)
void gemm_lds(const float* __restrict__ x,
              const float* __restrict__ w1,
              unsigned short* __restrict__ part) {
    __shared__ __align__(16) char smem[2][24576];   // [A 8KB][B 16KB] per buf

    const int tid = threadIdx.x;
    const int l   = tid & 63;
    const int wv  = tid >> 6;          // 0..7
    const int wm  = wv & 1;            // wave m index (2)
    const int wn  = wv >> 1;           // wave n index (4)

    // bijective XCD-chunked swizzle (NWG % 8 == 0): the 8 blocks sharing a
    // k-segment are logically consecutive -> land on one XCD's L2.
    const int hw      = blockIdx.y * 8 + blockIdx.x;
    const int logical = (hw & 7) * (NWG / 8) + (hw >> 3);
    const int s  = logical >> 3;
    const int mt = logical & 7;

    const int m0 = mt * 128;
    const int k0 = s * KSEG;

    // A staging: thread -> (row ar = tid>>2, 8-f32 granule ag = tid&3)
    const int ar = tid >> 2;            // 0..127
    const int ag = tid & 3;
    const float* asrc = x + (size_t)(m0 + ar) * K_DIM + k0 + ag * 8;
    const int aw_off = ar * 64 + ((ag ^ ((ar >> 1) & 3)) << 4);   // swizzled

    // B staging: thread -> (row br = tid>>1, 16-f32 half bh = tid&1)
    const int br = tid >> 1;            // 0..255 (B/W1 row)
    const int bh = tid & 1;
    const bool bvalid = br < N1;        // rows 200..255: no load, no write (junk cols only)
    const float* bsrc = w1 + (size_t)br * K_DIM + k0 + bh * 16;
    const int bg0 = bh * 2;             // first of two 8-elem granules
    const int bw_off0 = 8192 + br * 64 + (((bg0)     ^ ((br >> 1) & 3)) << 4);
    const int bw_off1 = 8192 + br * 64 + (((bg0 + 1) ^ ((br >> 1) & 3)) << 4);

    f32x16 acc[2][2];
    #pragma unroll
    for (int i = 0; i < 2; ++i)
        #pragma unroll
        for (int j = 0; j < 2; ++j)
            #pragma unroll
            for (int q = 0; q < 16; ++q) acc[i][j][q] = 0.f;

    float4 pA[2][2];                    // A reg slots, [step parity][2]
    float4 pB[4];                       // B(next) 16 f32

    // ---- prologue: stage step 0 directly; preload A(1), B(1) regs ----
    {
        float4 a0 = *(const float4*)asrc;
        float4 a1 = *(const float4*)(asrc + 4);
        float4 b0, b1, b2, b3;
        if (bvalid) {
            b0 = *(const float4*)bsrc;
            b1 = *(const float4*)(bsrc + 4);
            b2 = *(const float4*)(bsrc + 8);
            b3 = *(const float4*)(bsrc + 12);
        }
        // prefetch step-1 operands (stay in flight across the barrier)
        pA[1][0] = *(const float4*)(asrc + BK);
        pA[1][1] = *(const float4*)(asrc + BK + 4);
        if (bvalid) {
            const float* bp = bsrc + BK;
            pB[0] = *(const float4*)bp;
            pB[1] = *(const float4*)(bp + 4);
            pB[2] = *(const float4*)(bp + 8);
            pB[3] = *(const float4*)(bp + 12);
        }
        *(bf16x8*)(smem[0] + aw_off) = cvt8(a0, a1);
        if (bvalid) {
            *(bf16x8*)(smem[0] + bw_off0) = cvt8(b0, b1);
            *(bf16x8*)(smem[0] + bw_off1) = cvt8(b2, b3);
        }
    }
    lgkm_barrier();

    const int fr = l & 31;              // fragment row/col
    const int fh = (l >> 5) * 16;       // 16B half within 32B k-chunk

    #pragma unroll
    for (int it = 0; it < KSTEPS; ++it) {
        const int cur = it & 1;
        const bool more = (it + 1) < KSTEPS;

        // issue A(it+2) register loads (consumed at step it+1 ph3);
        // compiler free to place within the step body
        if (more) {
            const int jn = (it + 2 < KSTEPS) ? (it + 2) : (KSTEPS - 1);
            pA[cur][0] = *(const float4*)(asrc + jn * BK);   // slot (it+2)&1 == cur
            pA[cur][1] = *(const float4*)(asrc + jn * BK + 4);
        }

        // swizzled ds_read + MFMA (32x32x16) on buf[cur].
        // wn==3, fn==1 (cols 224-255) skipped: 100% junk columns.
        const char* ab = smem[cur];
        const char* bb = smem[cur] + 8192;
        #pragma unroll
        for (int kk = 0; kk < 2; ++kk) {
            const int r0 = wm * 64 + fr;
            const int r1 = wm * 64 + 32 + fr;
            bf16x8 a0 = *(const bf16x8*)(ab + r0 * 64 + ((kk * 32 + fh) ^ (((r0 >> 1) & 3) << 4)));
            bf16x8 a1 = *(const bf16x8*)(ab + r1 * 64 + ((kk * 32 + fh) ^ (((r1 >> 1) & 3) << 4)));
            #pragma unroll
            for (int fn = 0; fn < 2; ++fn) {
                if (wn == 3 && fn == 1) continue;   // junk-only output cols
                const int n = wn * 64 + fn * 32 + fr;
                bf16x8 bv = *(const bf16x8*)(bb + n * 64 + ((kk * 32 + fh) ^ (((n >> 1) & 3) << 4)));
                acc[0][fn] = __builtin_amdgcn_mfma_f32_32x32x16_bf16(a0, bv, acc[0][fn], 0, 0, 0);
                acc[1][fn] = __builtin_amdgcn_mfma_f32_32x32x16_bf16(a1, bv, acc[1][fn], 0, 0, 0);
            }
        }

        // cvt + swizzled ds_write of A(it+1), B(it+1) into buf^1 (may be
        // interleaved with the MFMAs above -- distinct LDS buffers);
        // then issue B(it+2) into the freed pB regs.
        if (more) {
            char* nb = smem[cur ^ 1];
            *(bf16x8*)(nb + aw_off) = cvt8(pA[cur ^ 1][0], pA[cur ^ 1][1]);
            if (bvalid) {
                *(bf16x8*)(nb + bw_off0) = cvt8(pB[0], pB[1]);
                *(bf16x8*)(nb + bw_off1) = cvt8(pB[2], pB[3]);
                if ((it + 2) < KSTEPS) {
                    const float* bp = bsrc + (size_t)(it + 2) * BK;
                    pB[0] = *(const float4*)bp;
                    pB[1] = *(const float4*)(bp + 4);
                    pB[2] = *(const float4*)(bp + 8);
                    pB[3] = *(const float4*)(bp + 12);
                }
            }
            lgkm_barrier();   // LDS visible; global prefetch stays in flight
        }
    }

    // epilogue: store cols < 200 as bf16, part layout [s][m][n], ld = 200
    // C/D layout (m74/m101): col = l&31, row = (reg&3) + 8*(reg>>2) + 4*(l>>5)
    const int col = l & 31;
    const int rhi = (l >> 5) * 4;
    #pragma unroll
    for (int fm = 0; fm < 2; ++fm)
        #pragma unroll
        for (int fn = 0; fn < 2; ++fn) {
            const int gn = wn * 64 + fn * 32 + col;
            if (gn < N1) {
                const int gmb = m0 + wm * 64 + fm * 32 + rhi;
                #pragma unroll
                for (int r = 0; r < 16; ++r) {
                    const int gm = gmb + (r & 3) + 8 * (r >> 2);
                    __hip_bfloat16 hv = __float2bfloat16(acc[fm][fn][r]);
                    part[(size_t)s * HN + (size_t)gm * N1 + gn] = *(unsigned short*)&hv;
                }
            }
        }
}

// Kernel 2: dense deterministic s-reduction of bf16 partials -> f32 h1.
template <int KSPLIT>
__global__ __launch_bounds__(256)
void reduce_kernel(const unsigned short* __restrict__ part, float* __restrict__ h1) {
    const size_t f = ((size_t)blockIdx.x * 256 + threadIdx.x) * 2;   // < 204800
    float a0 = 0.f, a1 = 0.f;
    #pragma unroll 25
    for (int s = 0; s < KSPLIT; ++s) {
        const unsigned int v = *(const unsigned int*)(part + (size_t)s * HN + f);
        a0 += bf2f((unsigned short)(v & 0xFFFFu));
        a1 += bf2f((unsigned short)(v >> 16));
    }
    h1[f]     = a0;
    h1[f + 1] = a1;
}

// Kernel 3: fused LIF tail, latency-tolerant. One block per batch b.
__global__ __launch_bounds__(256)
void tail_kernel(const float* __restrict__ h1,
                 const float* __restrict__ w2, const float* __restrict__ w3,
                 float* __restrict__ out) {
    __shared__ float w2s[N2 * N1];                  // 40 KB
    __shared__ float w3s[N3 * N2];
    __shared__ unsigned long long msk[T_STEPS][4];

    const int b    = blockIdx.x;
    const int i    = threadIdx.x;
    const int wv   = i >> 6;
    const int lane = i & 63;

    for (int o = i; o < (N2 * N1) / 4; o += 256)
        ((float4*)w2s)[o] = ((const float4*)w2)[o];
    if (i < N3 * N2) w3s[i] = w3[i];

    float h[T_STEPS];
    #pragma unroll
    for (int t = 0; t < T_STEPS; ++t)
        h[t] = (i < N1) ? h1[(size_t)(t * BATCH + b) * N1 + i] : 0.f;

    float v1 = 0.f;
    #pragma unroll
    for (int t = 0; t < T_STEPS; ++t) {
        v1 += (h[t] - v1) * 0.5f;
        bool sp = (v1 - 1.0f) >= 0.f;
        unsigned long long m = __ballot(sp);
        if (sp) v1 = 0.f;
        if (lane == 0) msk[t][wv] = m;
    }
    __syncthreads();

    if (wv == 0) {
        float v2 = 0.f, v3 = 0.f;
        for (int t = 0; t < T_STEPS; ++t) {
            float h2 = 0.f;
            if (lane < N2) {
                #pragma unroll
                for (int w = 0; w < 4; ++w) {
                    unsigned long long m = msk[t][w];
                    while (m) {
                        int lz = __builtin_ctzll(m);
                        m &= m - 1;
                        h2 += w2s[lane * N1 + (w * 64 + lz)];
                    }
                }
            }
            v2 += (h2 - v2) * 0.5f;
            bool sp2 = (v2 - 1.0f) >= 0.f;
            unsigned long long bal2 = __ballot(sp2);
            if (sp2) v2 = 0.f;

            float h3 = 0.f;
            if (lane < N3) {
                unsigned long long m = bal2;
                while (m) {
                    int j = __builtin_ctzll(m);
                    m &= m - 1;
                    h3 += w3s[lane * N2 + j];
                }
            }
            v3 += (h3 - v3) * 0.5f;
            bool sp3 = (v3 - 1.0f) >= 0.f;
            if (lane < N3)
                out[(size_t)(t * BATCH + b) * N3 + lane] = sp3 ? 1.f : 0.f;
            if (sp3) v3 = 0.f;
        }
    }
}

extern "C" void kernel_launch(void* const* d_in, const int* in_sizes, int n_in,
                              void* d_out, int out_size, void* d_ws, size_t ws_size,
                              hipStream_t stream) {
    const float* x  = (const float*)d_in[0];   // [16,64,150,400] -> [1024][60000]
    const float* w1 = (const float*)d_in[1];   // [200][60000]
    const float* w2 = (const float*)d_in[2];   // [50][200]
    const float* w3 = (const float*)d_in[3];   // [2][50]
    float* out = (float*)d_out;                // [16][64][2]

    // ws layout: part bf16 [KSPLIT][1024][200], h1 f32
    const size_t h1_bytes  = (size_t)HN * 4;                 // 0.82 MB
    const size_t need125 = (size_t)125 * HN * 2 + h1_bytes;  // ~52 MB
    const bool big = ws_size >= need125;

    const int ksplit = big ? 125 : 25;
    unsigned short* part = (unsigned short*)d_ws;
    float* h1 = (float*)((char*)d_ws + (size_t)ksplit * HN * 2);

    if (big) {
        dim3 g(8, 125);
        gemm_lds<480, 15, 1000><<<g, 512, 0, stream>>>(x, w1, part);
        reduce_kernel<125><<<HN / 512, 256, 0, stream>>>(part, h1);
    } else {
        dim3 g(8, 25);
        gemm_lds<2400, 75, 200><<<g, 512, 0, stream>>>(x, w1, part);
        reduce_kernel<25><<<HN / 512, 256, 0, stream>>>(part, h1);
    }
    tail_kernel<<<BATCH, 256, 0, stream>>>(h1, w2, w3, out);
}